// Round 2
// baseline (334.449 us; speedup 1.0000x reference)
//
#include <hip/hip_runtime.h>

#define KI 32
#define BG_SAMPLE 100

// ws float layout (per batch b at b*224):
//   acc[224] = { cnt[32], cntk[32], sums d-major [4][32], valsum[32] }
// then mean[B][32*4] (row-major k*4+d) at B*224 + b*128
// then misc[B][4] = { sum_pair, l_reg, sum_bg, pad } at B*224+B*128 + b*4
// total = B*356 floats

static __device__ __forceinline__ float waveReduceSum(float v) {
#pragma unroll
  for (int off = 32; off > 0; off >>= 1) v += __shfl_down(v, off, 64);
  return v;
}

__global__ __launch_bounds__(256)
void pass1_kernel(const float* __restrict__ emb, const int* __restrict__ inst,
                  const float* __restrict__ kern, const float* __restrict__ tmask,
                  float* __restrict__ ws, int N, int bpb)
{
  const int b = blockIdx.y;
  __shared__ float acc[4][192];   // per-wave: cnt[32] | cntk[32] | sums[4][32]
  for (int i = threadIdx.x; i < 4 * 192; i += 256) (&acc[0][0])[i] = 0.f;
  __syncthreads();
  float* a = acc[threadIdx.x >> 6];

  const size_t off = (size_t)b * N;
  const int N4 = N >> 2;
  const int4*   L4 = (const int4*)(inst + off);
  const float4* T4 = (const float4*)(tmask + off);
  const float4* K4 = (const float4*)(kern + off);
  const float4* E0 = (const float4*)(emb + (size_t)b * 4 * N);
  const float4* E1 = E0 + N4;
  const float4* E2 = E1 + N4;
  const float4* E3 = E2 + N4;
  const int stride = bpb * 256;

  for (int v = blockIdx.x * 256 + threadIdx.x; v < N4; v += stride) {
    int4   L  = L4[v];
    float4 T  = T4[v];
    float4 Kk = K4[v];
    float4 e0 = E0[v], e1 = E1[v], e2 = E2[v], e3 = E3[v];
#define PX(lj, tj, kj, a0, a1, a2, a3)                        \
    {                                                         \
      int lab = (tj > 0.5f) ? (lj) : 0;                       \
      float m = ((kj) > 0.5f && lab != 0) ? 1.0f : 0.0f;      \
      atomicAdd(&a[lab], 1.0f);                               \
      atomicAdd(&a[32 + lab], m);                             \
      atomicAdd(&a[64 + lab],  m * (a0));                     \
      atomicAdd(&a[96 + lab],  m * (a1));                     \
      atomicAdd(&a[128 + lab], m * (a2));                     \
      atomicAdd(&a[160 + lab], m * (a3));                     \
    }
    PX(L.x, T.x, Kk.x, e0.x, e1.x, e2.x, e3.x)
    PX(L.y, T.y, Kk.y, e0.y, e1.y, e2.y, e3.y)
    PX(L.z, T.z, Kk.z, e0.z, e1.z, e2.z, e3.z)
    PX(L.w, T.w, Kk.w, e0.w, e1.w, e2.w, e3.w)
#undef PX
  }
  // scalar tail (N % 4 != 0), block x==0 only
  if (blockIdx.x == 0) {
    for (int i = (N4 << 2) + threadIdx.x; i < N; i += 256) {
      int lab = (tmask[off + i] > 0.5f) ? inst[off + i] : 0;
      float m = (kern[off + i] > 0.5f && lab != 0) ? 1.0f : 0.0f;
      const float* eb = emb + (size_t)b * 4 * N;
      atomicAdd(&a[lab], 1.0f);
      atomicAdd(&a[32 + lab], m);
      atomicAdd(&a[64 + lab],  m * eb[i]);
      atomicAdd(&a[96 + lab],  m * eb[(size_t)N + i]);
      atomicAdd(&a[128 + lab], m * eb[(size_t)2 * N + i]);
      atomicAdd(&a[160 + lab], m * eb[(size_t)3 * N + i]);
    }
  }
  __syncthreads();
  float* g = ws + (size_t)b * 224;
  for (int i = threadIdx.x; i < 192; i += 256) {
    float v = acc[0][i] + acc[1][i] + acc[2][i] + acc[3][i];
    if (v != 0.f) atomicAdd(&g[i], v);
  }
}

__global__ __launch_bounds__(256)
void stats_kernel(float* __restrict__ ws, int B)
{
  const int b = blockIdx.x;
  float* gacc  = ws + (size_t)b * 224;
  float* gmean = ws + (size_t)B * 224 + (size_t)b * 128;
  float* gmisc = ws + (size_t)B * 224 + (size_t)B * 128 + (size_t)b * 4;
  __shared__ float mean[KI][4];
  const int t = threadIdx.x;
  if (t < KI) {
    float inv = (t == 0) ? 0.f : 1.0f / fmaxf(gacc[32 + t], 1.0f);
#pragma unroll
    for (int d = 0; d < 4; ++d) {
      float m = gacc[64 + d * 32 + t] * inv;
      mean[t][d] = m;
      gmean[t * 4 + d] = m;
    }
  }
  __syncthreads();
  const float coef = 1.0f - expf(-10.0f / 32.0f);
  float lp = 0.f;
  for (int idx = t; idx < 31 * 31; idx += 256) {
    int i = 1 + idx / 31, j = 1 + idx % 31;
    if (i == j) continue;
    float d0 = mean[i][0] - mean[j][0];
    float d1 = mean[i][1] - mean[j][1];
    float d2 = mean[i][2] - mean[j][2];
    float d3 = mean[i][3] - mean[j][3];
    float pd = sqrtf(d0 * d0 + d1 * d1 + d2 * d2 + d3 * d3);
    float a = fmaxf(3.0f - coef * pd, 0.f);
    lp += logf(a * a + 1.f);
  }
  float lr = 0.f;
  for (int k = t; k < KI; k += 256) {
    float n = sqrtf(mean[k][0] * mean[k][0] + mean[k][1] * mean[k][1] +
                    mean[k][2] * mean[k][2] + mean[k][3] * mean[k][3]);
    lr += logf(n + 1.f);
  }
  float spw = waveReduceSum(lp);
  float lrw = waveReduceSum(lr);
  __shared__ float red[2][4];
  if ((t & 63) == 0) { red[0][t >> 6] = spw; red[1][t >> 6] = lrw; }
  __syncthreads();
  if (t == 0) {
    gmisc[0] = red[0][0] + red[0][1] + red[0][2] + red[0][3];
    gmisc[1] = (red[1][0] + red[1][1] + red[1][2] + red[1][3]) * (0.001f / 32.0f);
  }
}

__global__ __launch_bounds__(256)
void bg_kernel(const float* __restrict__ emb, const int* __restrict__ inst,
               const float* __restrict__ tmask, float* __restrict__ ws, int N, int B)
{
  const int b = blockIdx.x;
  const int t = threadIdx.x;
  const int lane = t & 63, wave = t >> 6;
  __shared__ int s_bgidx[BG_SAMPLE];
  __shared__ int s_count;
  __shared__ int s_wcnt[4];
  if (t == 0) s_count = 0;
  __syncthreads();
  const int*   instb = inst + (size_t)b * N;
  const float* tmb   = tmask + (size_t)b * N;

  for (int base = 0; base < N; base += 256) {
    if (s_count >= BG_SAMPLE) break;
    int i = base + t;
    bool p = false;
    if (i < N) {
      int lab = instb[i];
      if (tmb[i] <= 0.5f) lab = 0;
      p = (lab == 0);
    }
    unsigned long long m = __ballot(p);
    if (lane == 0) s_wcnt[wave] = __popcll(m);
    __syncthreads();
    int pos = s_count;
    for (int w = 0; w < wave; ++w) pos += s_wcnt[w];
    if (p) {
      pos += __popcll(m & ((1ull << lane) - 1ull));
      if (pos < BG_SAMPLE) s_bgidx[pos] = i;
    }
    __syncthreads();
    if (t == 0) s_count += s_wcnt[0] + s_wcnt[1] + s_wcnt[2] + s_wcnt[3];
    __syncthreads();
  }
  if (s_count < BG_SAMPLE) {
    for (int base = 0; base < N; base += 256) {
      if (s_count >= BG_SAMPLE) break;
      int i = base + t;
      bool p = false;
      if (i < N) {
        int lab = instb[i];
        if (tmb[i] <= 0.5f) lab = 0;
        p = (lab != 0);
      }
      unsigned long long m = __ballot(p);
      if (lane == 0) s_wcnt[wave] = __popcll(m);
      __syncthreads();
      int pos = s_count;
      for (int w = 0; w < wave; ++w) pos += s_wcnt[w];
      if (p) {
        pos += __popcll(m & ((1ull << lane) - 1ull));
        if (pos < BG_SAMPLE) s_bgidx[pos] = i;
      }
      __syncthreads();
      if (t == 0) s_count += s_wcnt[0] + s_wcnt[1] + s_wcnt[2] + s_wcnt[3];
      __syncthreads();
    }
  }
  __syncthreads();

  __shared__ float ebg[BG_SAMPLE][4];
  const float* embb = emb + (size_t)b * 4 * N;
  for (int j = t; j < BG_SAMPLE; j += 256) {
    int i = s_bgidx[j];
    ebg[j][0] = embb[i];
    ebg[j][1] = embb[(size_t)N + i];
    ebg[j][2] = embb[(size_t)2 * N + i];
    ebg[j][3] = embb[(size_t)3 * N + i];
  }
  __shared__ float mean[KI][4];
  float* gmean = ws + (size_t)B * 224 + (size_t)b * 128;
  if (t < 128) (&mean[0][0])[t] = gmean[t];
  __syncthreads();

  const float coef = 1.0f - expf(-10.0f / 32.0f);
  float local = 0.f;
  for (int idx = t; idx < 31 * BG_SAMPLE; idx += 256) {
    int k = 1 + idx / BG_SAMPLE, j = idx % BG_SAMPLE;
    float d0 = ebg[j][0] - mean[k][0];
    float d1 = ebg[j][1] - mean[k][1];
    float d2 = ebg[j][2] - mean[k][2];
    float d3 = ebg[j][3] - mean[k][3];
    float dd = sqrtf(d0 * d0 + d1 * d1 + d2 * d2 + d3 * d3);
    float a = fmaxf(3.0f - coef * dd, 0.f);
    local += logf(a * a + 1.f);
  }
  float w = waveReduceSum(local);
  __shared__ float red[4];
  if (lane == 0) red[wave] = w;
  __syncthreads();
  if (t == 0) {
    float* gmisc = ws + (size_t)B * 224 + (size_t)B * 128 + (size_t)b * 4;
    gmisc[2] = (red[0] + red[1] + red[2] + red[3]) * (1.0f / BG_SAMPLE);
  }
}

__global__ __launch_bounds__(256)
void pass2_kernel(const float* __restrict__ emb, const int* __restrict__ inst,
                  const float* __restrict__ tmask, const float* __restrict__ maxd,
                  float* __restrict__ ws, int N, int B, int bpb)
{
  const int b = blockIdx.y;
  const int t = threadIdx.x;
  __shared__ float meanT[4][KI];
  __shared__ float scal[KI];
  __shared__ float vacc[4][KI];
  float* gmean = ws + (size_t)B * 224 + (size_t)b * 128;
  if (t < 128) { int d = t & 3, k = t >> 2; meanT[d][k] = gmean[t]; }
  if (t < KI) scal[t] = expf(maxd[b * KI + t]);
  for (int i = t; i < 4 * KI; i += 256) (&vacc[0][0])[i] = 0.f;
  __syncthreads();

  float* va = vacc[t >> 6];
  const size_t off = (size_t)b * N;
  const int N4 = N >> 2;
  const int4*   L4 = (const int4*)(inst + off);
  const float4* T4 = (const float4*)(tmask + off);
  const float4* E0 = (const float4*)(emb + (size_t)b * 4 * N);
  const float4* E1 = E0 + N4;
  const float4* E2 = E1 + N4;
  const float4* E3 = E2 + N4;
  const int stride = bpb * 256;

  for (int v = blockIdx.x * 256 + t; v < N4; v += stride) {
    int4   L  = L4[v];
    float4 T  = T4[v];
    float4 e0 = E0[v], e1 = E1[v], e2 = E2[v], e3 = E3[v];
#define PX2(lj, tj, a0, a1, a2, a3)                                   \
    {                                                                 \
      int lab = (tj > 0.5f) ? (lj) : 0;                               \
      float d0 = (a0) - meanT[0][lab];                                \
      float d1 = (a1) - meanT[1][lab];                                \
      float d2 = (a2) - meanT[2][lab];                                \
      float d3 = (a3) - meanT[3][lab];                                \
      float dd = sqrtf(d0 * d0 + d1 * d1 + d2 * d2 + d3 * d3);        \
      float aa = fmaxf(scal[lab] * dd - 0.5f, 0.f);                   \
      atomicAdd(&va[lab], __logf(aa * aa + 1.f));                     \
    }
    PX2(L.x, T.x, e0.x, e1.x, e2.x, e3.x)
    PX2(L.y, T.y, e0.y, e1.y, e2.y, e3.y)
    PX2(L.z, T.z, e0.z, e1.z, e2.z, e3.z)
    PX2(L.w, T.w, e0.w, e1.w, e2.w, e3.w)
#undef PX2
  }
  if (blockIdx.x == 0) {
    const float* eb = emb + (size_t)b * 4 * N;
    for (int i = (N4 << 2) + t; i < N; i += 256) {
      int lab = (tmask[off + i] > 0.5f) ? inst[off + i] : 0;
      float d0 = eb[i]               - meanT[0][lab];
      float d1 = eb[(size_t)N + i]   - meanT[1][lab];
      float d2 = eb[(size_t)2*N + i] - meanT[2][lab];
      float d3 = eb[(size_t)3*N + i] - meanT[3][lab];
      float dd = sqrtf(d0 * d0 + d1 * d1 + d2 * d2 + d3 * d3);
      float aa = fmaxf(scal[lab] * dd - 0.5f, 0.f);
      atomicAdd(&va[lab], __logf(aa * aa + 1.f));
    }
  }
  __syncthreads();
  float* gval = ws + (size_t)b * 224 + 192;
  for (int i = t; i < KI; i += 256) {
    float v = vacc[0][i] + vacc[1][i] + vacc[2][i] + vacc[3][i];
    if (v != 0.f) atomicAdd(&gval[i], v);
  }
}

__global__ __launch_bounds__(64)
void final_kernel(const float* __restrict__ ws, float* __restrict__ out, int B)
{
  const int t = threadIdx.x;
  __shared__ float s[64];
  float tot = 0.f;
  if (t < B) {
    const float* gacc  = ws + (size_t)t * 224;
    const float* gmisc = ws + (size_t)B * 224 + (size_t)B * 128 + (size_t)t * 4;
    float lagg = 0.f;
    for (int k = 1; k < KI; ++k)
      lagg += gacc[192 + k] / fmaxf(gacc[k], 1.0f);
    lagg *= (1.0f / 31.0f);
    float ldis = (gmisc[0] + gmisc[2]) * (1.0f / 961.0f);  // (K-1)(K-2)+(K-1)
    tot = lagg + ldis + gmisc[1];
  }
  s[t] = tot;
  __syncthreads();
  if (t == 0) {
    float sum = 0.f;
    for (int b = 0; b < B; ++b) sum += s[b];
    out[0] = sum / (float)B;
  }
}

extern "C" void kernel_launch(void* const* d_in, const int* in_sizes, int n_in,
                              void* d_out, int out_size, void* d_ws, size_t ws_size,
                              hipStream_t stream)
{
  const float* emb   = (const float*)d_in[0];
  const int*   inst  = (const int*)d_in[1];
  const float* kern  = (const float*)d_in[2];
  const float* tmask = (const float*)d_in[3];
  const float* maxd  = (const float*)d_in[5];
  float* out = (float*)d_out;
  float* ws  = (float*)d_ws;

  const int B = in_sizes[5] / KI;          // 16
  const int N = in_sizes[1] / B;           // 409600
  const int bpb = 128;

  if (ws_size < (size_t)B * 356 * sizeof(float)) return;

  hipMemsetAsync(d_ws, 0, (size_t)B * 356 * sizeof(float), stream);
  pass1_kernel<<<dim3(bpb, B), 256, 0, stream>>>(emb, inst, kern, tmask, ws, N, bpb);
  stats_kernel<<<B, 256, 0, stream>>>(ws, B);
  bg_kernel<<<B, 256, 0, stream>>>(emb, inst, tmask, ws, N, B);
  pass2_kernel<<<dim3(bpb, B), 256, 0, stream>>>(emb, inst, tmask, maxd, ws, N, B, bpb);
  final_kernel<<<1, 64, 0, stream>>>(ws, out, B);
}

// Round 3
// 170.723 us; speedup vs baseline: 1.9590x; 1.9590x over previous
//
#include <hip/hip_runtime.h>

#define KI 32
#define BG_SAMPLE 100

// ws float layout (per batch b at b*224):
//   acc[224] = { cnt[32], cntk[32], sums d-major [4][32], valsum[32] }
// then mean[B][32*4] (row-major k*4+d) at B*224 + b*128
// then misc[B][4] = { sum_pair, l_reg, sum_bg, pad } at B*224+B*128 + b*4
// total = B*356 floats

static __device__ __forceinline__ unsigned lds_off(const void* p) {
  // addrspacecast(3->generic) puts the LDS byte offset in the low 32 bits
  return (unsigned)(unsigned long long)p;
}
static __device__ __forceinline__ unsigned pkrtz(float a, float b) {
  unsigned d;
  asm("v_cvt_pkrtz_f16_f32 %0, %1, %2" : "=v"(d) : "v"(a), "v"(b));
  return d;
}
static __device__ __forceinline__ void ds_pk_add(unsigned addr, unsigned data) {
  asm volatile("ds_pk_add_f16 %0, %1" :: "v"(addr), "v"(data) : "memory");
}
static __device__ __forceinline__ float cvt_lo(unsigned u) {
  float f; asm("v_cvt_f32_f16 %0, %1" : "=v"(f) : "v"(u & 0xffffu)); return f;
}
static __device__ __forceinline__ float cvt_hi(unsigned u) {
  float f; asm("v_cvt_f32_f16 %0, %1" : "=v"(f) : "v"(u >> 16)); return f;
}

static __device__ __forceinline__ float waveReduceSum(float v) {
#pragma unroll
  for (int off = 32; off > 0; off >>= 1) v += __shfl_down(v, off, 64);
  return v;
}

__global__ __launch_bounds__(256)
void pass1_kernel(const float* __restrict__ emb, const int* __restrict__ inst,
                  const float* __restrict__ kern, const float* __restrict__ tmask,
                  float* __restrict__ ws, int N, int bpb)
{
  const int b = blockIdx.y;
  __shared__ unsigned acc[4][96];   // per-wave: cntk[32] | pk01[32] | pk23[32]
  for (int i = threadIdx.x; i < 4 * 96; i += 256) (&acc[0][0])[i] = 0u;
  __syncthreads();
  const int wave = threadIdx.x >> 6;
  unsigned* a = acc[wave];
  const unsigned base = lds_off(a);

  const size_t off = (size_t)b * N;
  const int N4 = N >> 2;
  const int4*   L4 = (const int4*)(inst + off);
  const float4* T4 = (const float4*)(tmask + off);
  const float4* K4 = (const float4*)(kern + off);
  const float4* E0 = (const float4*)(emb + (size_t)b * 4 * N);
  const float4* E1 = E0 + N4;
  const float4* E2 = E1 + N4;
  const float4* E3 = E2 + N4;
  const int stride = bpb * 256;

  for (int v = blockIdx.x * 256 + threadIdx.x; v < N4; v += stride) {
    int4   L  = L4[v];
    float4 T  = T4[v];
    float4 Kk = K4[v];
    float4 e0 = E0[v], e1 = E1[v], e2 = E2[v], e3 = E3[v];
#define PX(lj, tj, kj, a0, a1, a2, a3)                                  \
    {                                                                   \
      unsigned lab = (unsigned)((tj > 0.5f) ? (lj) : 0) & 31u;          \
      unsigned ku = (kj > 0.5f) ? 1u : 0u;                              \
      float m = (float)ku;                                              \
      atomicAdd(&a[lab], ku);                                           \
      ds_pk_add(base + 128u + (lab << 2), pkrtz(m * (a0), m * (a1)));   \
      ds_pk_add(base + 256u + (lab << 2), pkrtz(m * (a2), m * (a3)));   \
    }
    PX(L.x, T.x, Kk.x, e0.x, e1.x, e2.x, e3.x)
    PX(L.y, T.y, Kk.y, e0.y, e1.y, e2.y, e3.y)
    PX(L.z, T.z, Kk.z, e0.z, e1.z, e2.z, e3.z)
    PX(L.w, T.w, Kk.w, e0.w, e1.w, e2.w, e3.w)
#undef PX
  }
  // scalar tail (N % 4 != 0), block x==0 only
  if (blockIdx.x == 0) {
    const float* eb = emb + (size_t)b * 4 * N;
    for (int i = (N4 << 2) + threadIdx.x; i < N; i += 256) {
      unsigned lab = (unsigned)((tmask[off + i] > 0.5f) ? inst[off + i] : 0) & 31u;
      unsigned ku = (kern[off + i] > 0.5f) ? 1u : 0u;
      float m = (float)ku;
      atomicAdd(&a[lab], ku);
      ds_pk_add(base + 128u + (lab << 2),
                pkrtz(m * eb[i], m * eb[(size_t)N + i]));
      ds_pk_add(base + 256u + (lab << 2),
                pkrtz(m * eb[(size_t)2 * N + i], m * eb[(size_t)3 * N + i]));
    }
  }
  __syncthreads();
  float* g = ws + (size_t)b * 224;
  for (int i = threadIdx.x; i < 96; i += 256) {
    unsigned u0 = acc[0][i], u1 = acc[1][i], u2 = acc[2][i], u3 = acc[3][i];
    if (i < 32) {
      unsigned s = u0 + u1 + u2 + u3;
      if (s) atomicAdd(&g[32 + i], (float)s);
    } else {
      int k = i & 31;
      int dlo = (i < 64) ? 0 : 2;
      float slo = cvt_lo(u0) + cvt_lo(u1) + cvt_lo(u2) + cvt_lo(u3);
      float shi = cvt_hi(u0) + cvt_hi(u1) + cvt_hi(u2) + cvt_hi(u3);
      if (slo != 0.f) atomicAdd(&g[64 + dlo * 32 + k], slo);
      if (shi != 0.f) atomicAdd(&g[64 + (dlo + 1) * 32 + k], shi);
    }
  }
}

__global__ __launch_bounds__(256)
void stats_kernel(float* __restrict__ ws, int B)
{
  const int b = blockIdx.x;
  float* gacc  = ws + (size_t)b * 224;
  float* gmean = ws + (size_t)B * 224 + (size_t)b * 128;
  float* gmisc = ws + (size_t)B * 224 + (size_t)B * 128 + (size_t)b * 4;
  __shared__ float mean[KI][4];
  const int t = threadIdx.x;
  if (t < KI) {
    float inv = (t == 0) ? 0.f : 1.0f / fmaxf(gacc[32 + t], 1.0f);
#pragma unroll
    for (int d = 0; d < 4; ++d) {
      float m = gacc[64 + d * 32 + t] * inv;
      mean[t][d] = m;
      gmean[t * 4 + d] = m;
    }
  }
  __syncthreads();
  const float coef = 1.0f - expf(-10.0f / 32.0f);
  float lp = 0.f;
  for (int idx = t; idx < 31 * 31; idx += 256) {
    int i = 1 + idx / 31, j = 1 + idx % 31;
    if (i == j) continue;
    float d0 = mean[i][0] - mean[j][0];
    float d1 = mean[i][1] - mean[j][1];
    float d2 = mean[i][2] - mean[j][2];
    float d3 = mean[i][3] - mean[j][3];
    float pd = sqrtf(d0 * d0 + d1 * d1 + d2 * d2 + d3 * d3);
    float a = fmaxf(3.0f - coef * pd, 0.f);
    lp += logf(a * a + 1.f);
  }
  float lr = 0.f;
  for (int k = t; k < KI; k += 256) {
    float n = sqrtf(mean[k][0] * mean[k][0] + mean[k][1] * mean[k][1] +
                    mean[k][2] * mean[k][2] + mean[k][3] * mean[k][3]);
    lr += logf(n + 1.f);
  }
  float spw = waveReduceSum(lp);
  float lrw = waveReduceSum(lr);
  __shared__ float red[2][4];
  if ((t & 63) == 0) { red[0][t >> 6] = spw; red[1][t >> 6] = lrw; }
  __syncthreads();
  if (t == 0) {
    gmisc[0] = red[0][0] + red[0][1] + red[0][2] + red[0][3];
    gmisc[1] = (red[1][0] + red[1][1] + red[1][2] + red[1][3]) * (0.001f / 32.0f);
  }
}

__global__ __launch_bounds__(256)
void bg_kernel(const float* __restrict__ emb, const int* __restrict__ inst,
               const float* __restrict__ tmask, float* __restrict__ ws, int N, int B)
{
  const int b = blockIdx.x;
  const int t = threadIdx.x;
  const int lane = t & 63, wave = t >> 6;
  __shared__ int s_bgidx[BG_SAMPLE];
  __shared__ int s_count;
  __shared__ int s_wcnt[4];
  if (t == 0) s_count = 0;
  __syncthreads();
  const int*   instb = inst + (size_t)b * N;
  const float* tmb   = tmask + (size_t)b * N;

  for (int base = 0; base < N; base += 256) {
    if (s_count >= BG_SAMPLE) break;
    int i = base + t;
    bool p = false;
    if (i < N) {
      int lab = instb[i];
      if (tmb[i] <= 0.5f) lab = 0;
      p = (lab == 0);
    }
    unsigned long long m = __ballot(p);
    if (lane == 0) s_wcnt[wave] = __popcll(m);
    __syncthreads();
    int pos = s_count;
    for (int w = 0; w < wave; ++w) pos += s_wcnt[w];
    if (p) {
      pos += __popcll(m & ((1ull << lane) - 1ull));
      if (pos < BG_SAMPLE) s_bgidx[pos] = i;
    }
    __syncthreads();
    if (t == 0) s_count += s_wcnt[0] + s_wcnt[1] + s_wcnt[2] + s_wcnt[3];
    __syncthreads();
  }
  if (s_count < BG_SAMPLE) {
    for (int base = 0; base < N; base += 256) {
      if (s_count >= BG_SAMPLE) break;
      int i = base + t;
      bool p = false;
      if (i < N) {
        int lab = instb[i];
        if (tmb[i] <= 0.5f) lab = 0;
        p = (lab != 0);
      }
      unsigned long long m = __ballot(p);
      if (lane == 0) s_wcnt[wave] = __popcll(m);
      __syncthreads();
      int pos = s_count;
      for (int w = 0; w < wave; ++w) pos += s_wcnt[w];
      if (p) {
        pos += __popcll(m & ((1ull << lane) - 1ull));
        if (pos < BG_SAMPLE) s_bgidx[pos] = i;
      }
      __syncthreads();
      if (t == 0) s_count += s_wcnt[0] + s_wcnt[1] + s_wcnt[2] + s_wcnt[3];
      __syncthreads();
    }
  }
  __syncthreads();

  __shared__ float ebg[BG_SAMPLE][4];
  const float* embb = emb + (size_t)b * 4 * N;
  for (int j = t; j < BG_SAMPLE; j += 256) {
    int i = s_bgidx[j];
    ebg[j][0] = embb[i];
    ebg[j][1] = embb[(size_t)N + i];
    ebg[j][2] = embb[(size_t)2 * N + i];
    ebg[j][3] = embb[(size_t)3 * N + i];
  }
  __shared__ float mean[KI][4];
  float* gmean = ws + (size_t)B * 224 + (size_t)b * 128;
  if (t < 128) (&mean[0][0])[t] = gmean[t];
  __syncthreads();

  const float coef = 1.0f - expf(-10.0f / 32.0f);
  float local = 0.f;
  for (int idx = t; idx < 31 * BG_SAMPLE; idx += 256) {
    int k = 1 + idx / BG_SAMPLE, j = idx % BG_SAMPLE;
    float d0 = ebg[j][0] - mean[k][0];
    float d1 = ebg[j][1] - mean[k][1];
    float d2 = ebg[j][2] - mean[k][2];
    float d3 = ebg[j][3] - mean[k][3];
    float dd = sqrtf(d0 * d0 + d1 * d1 + d2 * d2 + d3 * d3);
    float a = fmaxf(3.0f - coef * dd, 0.f);
    local += logf(a * a + 1.f);
  }
  float w = waveReduceSum(local);
  __shared__ float red[4];
  if (lane == 0) red[wave] = w;
  __syncthreads();
  if (t == 0) {
    float* gmisc = ws + (size_t)B * 224 + (size_t)B * 128 + (size_t)b * 4;
    gmisc[2] = (red[0] + red[1] + red[2] + red[3]) * (1.0f / BG_SAMPLE);
  }
}

__global__ __launch_bounds__(256)
void pass2_kernel(const float* __restrict__ emb, const int* __restrict__ inst,
                  const float* __restrict__ tmask, const float* __restrict__ maxd,
                  float* __restrict__ ws, int N, int B, int bpb)
{
  const int b = blockIdx.y;
  const int t = threadIdx.x;
  __shared__ float meanT[4][KI];
  __shared__ float scal[KI];
  __shared__ unsigned vacc[4][KI];   // pk (valsum, cnt) per wave copy
  float* gmean = ws + (size_t)B * 224 + (size_t)b * 128;
  if (t < 128) { int d = t & 3, k = t >> 2; meanT[d][k] = gmean[t]; }
  if (t < KI) scal[t] = expf(maxd[b * KI + t]);
  for (int i = t; i < 4 * KI; i += 256) (&vacc[0][0])[i] = 0u;
  __syncthreads();

  unsigned* va = vacc[t >> 6];
  const unsigned vbase = lds_off(va);
  const size_t off = (size_t)b * N;
  const int N4 = N >> 2;
  const int4*   L4 = (const int4*)(inst + off);
  const float4* T4 = (const float4*)(tmask + off);
  const float4* E0 = (const float4*)(emb + (size_t)b * 4 * N);
  const float4* E1 = E0 + N4;
  const float4* E2 = E1 + N4;
  const float4* E3 = E2 + N4;
  const int stride = bpb * 256;

  for (int v = blockIdx.x * 256 + t; v < N4; v += stride) {
    int4   L  = L4[v];
    float4 T  = T4[v];
    float4 e0 = E0[v], e1 = E1[v], e2 = E2[v], e3 = E3[v];
#define PX2(lj, tj, a0, a1, a2, a3)                                   \
    {                                                                 \
      unsigned lab = (unsigned)((tj > 0.5f) ? (lj) : 0) & 31u;        \
      float d0 = (a0) - meanT[0][lab];                                \
      float d1 = (a1) - meanT[1][lab];                                \
      float d2 = (a2) - meanT[2][lab];                                \
      float d3 = (a3) - meanT[3][lab];                                \
      float dd = sqrtf(d0 * d0 + d1 * d1 + d2 * d2 + d3 * d3);        \
      float aa = fmaxf(scal[lab] * dd - 0.5f, 0.f);                   \
      ds_pk_add(vbase + (lab << 2), pkrtz(__logf(aa * aa + 1.f), 1.0f)); \
    }
    PX2(L.x, T.x, e0.x, e1.x, e2.x, e3.x)
    PX2(L.y, T.y, e0.y, e1.y, e2.y, e3.y)
    PX2(L.z, T.z, e0.z, e1.z, e2.z, e3.z)
    PX2(L.w, T.w, e0.w, e1.w, e2.w, e3.w)
#undef PX2
  }
  if (blockIdx.x == 0) {
    const float* eb = emb + (size_t)b * 4 * N;
    for (int i = (N4 << 2) + t; i < N; i += 256) {
      unsigned lab = (unsigned)((tmask[off + i] > 0.5f) ? inst[off + i] : 0) & 31u;
      float d0 = eb[i]               - meanT[0][lab];
      float d1 = eb[(size_t)N + i]   - meanT[1][lab];
      float d2 = eb[(size_t)2*N + i] - meanT[2][lab];
      float d3 = eb[(size_t)3*N + i] - meanT[3][lab];
      float dd = sqrtf(d0 * d0 + d1 * d1 + d2 * d2 + d3 * d3);
      float aa = fmaxf(scal[lab] * dd - 0.5f, 0.f);
      ds_pk_add(vbase + (lab << 2), pkrtz(__logf(aa * aa + 1.f), 1.0f));
    }
  }
  __syncthreads();
  float* g = ws + (size_t)b * 224;
  for (int i = t; i < KI; i += 256) {
    unsigned u0 = vacc[0][i], u1 = vacc[1][i], u2 = vacc[2][i], u3 = vacc[3][i];
    float slo = cvt_lo(u0) + cvt_lo(u1) + cvt_lo(u2) + cvt_lo(u3);  // valsum
    float shi = cvt_hi(u0) + cvt_hi(u1) + cvt_hi(u2) + cvt_hi(u3);  // cnt
    if (slo != 0.f) atomicAdd(&g[192 + i], slo);
    if (shi != 0.f) atomicAdd(&g[i], shi);
  }
}

__global__ __launch_bounds__(64)
void final_kernel(const float* __restrict__ ws, float* __restrict__ out, int B)
{
  const int t = threadIdx.x;
  __shared__ float s[64];
  float tot = 0.f;
  if (t < B) {
    const float* gacc  = ws + (size_t)t * 224;
    const float* gmisc = ws + (size_t)B * 224 + (size_t)B * 128 + (size_t)t * 4;
    float lagg = 0.f;
    for (int k = 1; k < KI; ++k)
      lagg += gacc[192 + k] / fmaxf(gacc[k], 1.0f);
    lagg *= (1.0f / 31.0f);
    float ldis = (gmisc[0] + gmisc[2]) * (1.0f / 961.0f);  // (K-1)(K-2)+(K-1)
    tot = lagg + ldis + gmisc[1];
  }
  s[t] = tot;
  __syncthreads();
  if (t == 0) {
    float sum = 0.f;
    for (int b = 0; b < B; ++b) sum += s[b];
    out[0] = sum / (float)B;
  }
}

extern "C" void kernel_launch(void* const* d_in, const int* in_sizes, int n_in,
                              void* d_out, int out_size, void* d_ws, size_t ws_size,
                              hipStream_t stream)
{
  const float* emb   = (const float*)d_in[0];
  const int*   inst  = (const int*)d_in[1];
  const float* kern  = (const float*)d_in[2];
  const float* tmask = (const float*)d_in[3];
  const float* maxd  = (const float*)d_in[5];
  float* out = (float*)d_out;
  float* ws  = (float*)d_ws;

  const int B = in_sizes[5] / KI;          // 16
  const int N = in_sizes[1] / B;           // 409600
  const int bpb = 128;

  if (ws_size < (size_t)B * 356 * sizeof(float)) return;

  hipMemsetAsync(d_ws, 0, (size_t)B * 356 * sizeof(float), stream);
  pass1_kernel<<<dim3(bpb, B), 256, 0, stream>>>(emb, inst, kern, tmask, ws, N, bpb);
  stats_kernel<<<B, 256, 0, stream>>>(ws, B);
  bg_kernel<<<B, 256, 0, stream>>>(emb, inst, tmask, ws, N, B);
  pass2_kernel<<<dim3(bpb, B), 256, 0, stream>>>(emb, inst, tmask, maxd, ws, N, B, bpb);
  final_kernel<<<1, 64, 0, stream>>>(ws, out, B);
}

// Round 4
// 122.424 us; speedup vs baseline: 2.7319x; 1.3945x over previous
//
#include <hip/hip_runtime.h>

#define KI 32
#define BG_SAMPLE 100

// ws float layout (per batch b at b*224):
//   acc[224] = { cnt[32], cntk[32], sums d-major [4][32], valsum[32] }
// then mean[B][32*4] (row-major k*4+d) at B*224 + b*128
// then misc[B][4] = { sum_pair, l_reg, sum_bg, pad } at B*224+B*128 + b*4
// total = B*356 floats

typedef __attribute__((ext_vector_type(8))) short short8;
typedef __attribute__((ext_vector_type(4))) float f32x4;
typedef union { unsigned u[4]; short8 v; } frag_u;

static __device__ __forceinline__ unsigned lds_off(const void* p) {
  return (unsigned)(unsigned long long)p;
}
static __device__ __forceinline__ unsigned pkrtz(float a, float b) {
  unsigned d;
  asm("v_cvt_pkrtz_f16_f32 %0, %1, %2" : "=v"(d) : "v"(a), "v"(b));
  return d;
}
static __device__ __forceinline__ void ds_pk_add(unsigned addr, unsigned data) {
  asm volatile("ds_pk_add_f16 %0, %1" :: "v"(addr), "v"(data) : "memory");
}
static __device__ __forceinline__ float cvt_lo(unsigned u) {
  float f; asm("v_cvt_f32_f16 %0, %1" : "=v"(f) : "v"(u & 0xffffu)); return f;
}
static __device__ __forceinline__ float cvt_hi(unsigned u) {
  float f; asm("v_cvt_f32_f16 %0, %1" : "=v"(f) : "v"(u >> 16)); return f;
}
static __device__ __forceinline__ unsigned cvtpk_bf16(float lo, float hi) {
  unsigned d;
  asm("v_cvt_pk_bf16_f32 %0, %1, %2" : "=v"(d) : "v"(lo), "v"(hi));
  return d;
}
static __device__ __forceinline__ unsigned ohpair(int la, int lb_, int r) {
  return ((la == r) ? 0x3F80u : 0u) | ((lb_ == r) ? 0x3F800000u : 0u);
}

static __device__ __forceinline__ float waveReduceSum(float v) {
#pragma unroll
  for (int off = 32; off > 0; off >>= 1) v += __shfl_down(v, off, 64);
  return v;
}

// ---------------- pass1: MFMA one-hot binning ----------------
// Per wave: stage composed labels (lab if tm&&kern else 0) for a 256-px tile,
// then 8 sub-iters of 32 px: D[label][col] += onehot(label) x features,
// cols 0-3 = e0..e3 (raw), col 4 = 1 (cntk). Row 0 = trash bin.
__global__ __launch_bounds__(256)
void pass1_kernel(const float* __restrict__ emb, const int* __restrict__ inst,
                  const float* __restrict__ kern, const float* __restrict__ tmask,
                  float* __restrict__ ws, int N, int bpb)
{
  const int b = blockIdx.y;
  const int t = threadIdx.x;
  const int lane = t & 63, w = t >> 6;
  const int c = lane & 15, g = lane >> 4;
  __shared__ int s_lab[4][256];
  __shared__ float s_acc[160];   // [2 groups][16 rows][5 cols]
  for (int i = t; i < 160; i += 256) s_acc[i] = 0.f;
  __syncthreads();

  const size_t off = (size_t)b * N;
  const int*   instb = inst + off;
  const float* kernb = kern + off;
  const float* tmb   = tmask + off;
  const float* embb  = emb + (size_t)b * 4 * N;
  float* gout = ws + (size_t)b * 224;

  f32x4 acc0 = {0.f, 0.f, 0.f, 0.f};
  f32x4 acc1 = {0.f, 0.f, 0.f, 0.f};

  const int waves_total = bpb * 4;
  const int wave_id = blockIdx.x * 4 + w;
  const int tiles = N >> 8;

  for (int tile = wave_id; tile < tiles; tile += waves_total) {
    const int px0 = tile << 8;
    {
      int4   L  = *(const int4*)(instb + px0 + lane * 4);
      float4 Tm = *(const float4*)(tmb + px0 + lane * 4);
      float4 Kk = *(const float4*)(kernb + px0 + lane * 4);
      int4 lb;
      lb.x = (Tm.x > 0.5f && Kk.x > 0.5f) ? L.x : 0;
      lb.y = (Tm.y > 0.5f && Kk.y > 0.5f) ? L.y : 0;
      lb.z = (Tm.z > 0.5f && Kk.z > 0.5f) ? L.z : 0;
      lb.w = (Tm.w > 0.5f && Kk.w > 0.5f) ? L.w : 0;
      *(int4*)&s_lab[w][lane * 4] = lb;
    }
    asm volatile("s_waitcnt lgkmcnt(0)" ::: "memory");
#pragma unroll
    for (int j = 0; j < 8; ++j) {
      const int p8 = j * 32 + g * 8;   // lane's 8 pixels within tile (k-slice)
      int4 l0 = *(const int4*)&s_lab[w][p8];
      int4 l1 = *(const int4*)&s_lab[w][p8 + 4];
      frag_u fa0, fa1, fb;
      fa0.u[0] = ohpair(l0.x, l0.y, c);
      fa0.u[1] = ohpair(l0.z, l0.w, c);
      fa0.u[2] = ohpair(l1.x, l1.y, c);
      fa0.u[3] = ohpair(l1.z, l1.w, c);
      const int r1 = c + 16;
      fa1.u[0] = ohpair(l0.x, l0.y, r1);
      fa1.u[1] = ohpair(l0.z, l0.w, r1);
      fa1.u[2] = ohpair(l1.x, l1.y, r1);
      fa1.u[3] = ohpair(l1.z, l1.w, r1);
      if (c < 4) {
        const float* ep = embb + (size_t)c * N + px0 + p8;
        float4 e0 = *(const float4*)(ep);
        float4 e1 = *(const float4*)(ep + 4);
        fb.u[0] = cvtpk_bf16(e0.x, e0.y);
        fb.u[1] = cvtpk_bf16(e0.z, e0.w);
        fb.u[2] = cvtpk_bf16(e1.x, e1.y);
        fb.u[3] = cvtpk_bf16(e1.z, e1.w);
      } else if (c == 4) {
        fb.u[0] = fb.u[1] = fb.u[2] = fb.u[3] = 0x3F803F80u;  // col4 = 1.0
      } else {
        fb.u[0] = fb.u[1] = fb.u[2] = fb.u[3] = 0u;
      }
      acc0 = __builtin_amdgcn_mfma_f32_16x16x32_bf16(fa0.v, fb.v, acc0, 0, 0, 0);
      acc1 = __builtin_amdgcn_mfma_f32_16x16x32_bf16(fa1.v, fb.v, acc1, 0, 0, 0);
    }
  }

  // lane holds D[row = g*4+jj][col = c]; reduce across waves in LDS
  if (c < 5) {
#pragma unroll
    for (int jj = 0; jj < 4; ++jj) {
      int row = g * 4 + jj;
      atomicAdd(&s_acc[(0 * 16 + row) * 5 + c], acc0[jj]);
      atomicAdd(&s_acc[(1 * 16 + row) * 5 + c], acc1[jj]);
    }
  }
  // scalar tail (N % 256 != 0) -> direct global atomics (never for 640x640)
  if ((N & 255) != 0 && blockIdx.x == 0) {
    for (int i = (tiles << 8) + t; i < N; i += 256) {
      int lab = (tmb[i] > 0.5f && kernb[i] > 0.5f) ? instb[i] : 0;
      atomicAdd(&gout[32 + lab], 1.f);
#pragma unroll
      for (int d = 0; d < 4; ++d)
        atomicAdd(&gout[64 + d * 32 + lab], embb[(size_t)d * N + i]);
    }
  }
  __syncthreads();
  if (t < 160) {
    float v = s_acc[t];
    if (v != 0.f) {
      int gg = t / 80, rem = t % 80;
      int row = rem / 5, cc = rem % 5;
      int label = gg * 16 + row;
      if (cc < 4) atomicAdd(&gout[64 + cc * 32 + label], v);
      else        atomicAdd(&gout[32 + label], v);
    }
  }
}

__global__ __launch_bounds__(256)
void stats_kernel(float* __restrict__ ws, int B)
{
  const int b = blockIdx.x;
  float* gacc  = ws + (size_t)b * 224;
  float* gmean = ws + (size_t)B * 224 + (size_t)b * 128;
  float* gmisc = ws + (size_t)B * 224 + (size_t)B * 128 + (size_t)b * 4;
  __shared__ float mean[KI][4];
  const int t = threadIdx.x;
  if (t < KI) {
    float inv = (t == 0) ? 0.f : 1.0f / fmaxf(gacc[32 + t], 1.0f);
#pragma unroll
    for (int d = 0; d < 4; ++d) {
      float m = gacc[64 + d * 32 + t] * inv;
      mean[t][d] = m;
      gmean[t * 4 + d] = m;
    }
  }
  __syncthreads();
  const float coef = 1.0f - expf(-10.0f / 32.0f);
  float lp = 0.f;
  for (int idx = t; idx < 31 * 31; idx += 256) {
    int i = 1 + idx / 31, j = 1 + idx % 31;
    if (i == j) continue;
    float d0 = mean[i][0] - mean[j][0];
    float d1 = mean[i][1] - mean[j][1];
    float d2 = mean[i][2] - mean[j][2];
    float d3 = mean[i][3] - mean[j][3];
    float pd = sqrtf(d0 * d0 + d1 * d1 + d2 * d2 + d3 * d3);
    float a = fmaxf(3.0f - coef * pd, 0.f);
    lp += logf(a * a + 1.f);
  }
  float lr = 0.f;
  for (int k = t; k < KI; k += 256) {
    float n = sqrtf(mean[k][0] * mean[k][0] + mean[k][1] * mean[k][1] +
                    mean[k][2] * mean[k][2] + mean[k][3] * mean[k][3]);
    lr += logf(n + 1.f);
  }
  float spw = waveReduceSum(lp);
  float lrw = waveReduceSum(lr);
  __shared__ float red[2][4];
  if ((t & 63) == 0) { red[0][t >> 6] = spw; red[1][t >> 6] = lrw; }
  __syncthreads();
  if (t == 0) {
    gmisc[0] = red[0][0] + red[0][1] + red[0][2] + red[0][3];
    gmisc[1] = (red[1][0] + red[1][1] + red[1][2] + red[1][3]) * (0.001f / 32.0f);
  }
}

__global__ __launch_bounds__(256)
void bg_kernel(const float* __restrict__ emb, const int* __restrict__ inst,
               const float* __restrict__ tmask, float* __restrict__ ws, int N, int B)
{
  const int b = blockIdx.x;
  const int t = threadIdx.x;
  const int lane = t & 63, wave = t >> 6;
  __shared__ int s_bgidx[BG_SAMPLE];
  __shared__ int s_count;
  __shared__ int s_wcnt[4];
  if (t == 0) s_count = 0;
  __syncthreads();
  const int*   instb = inst + (size_t)b * N;
  const float* tmb   = tmask + (size_t)b * N;

  for (int base = 0; base < N; base += 256) {
    if (s_count >= BG_SAMPLE) break;
    int i = base + t;
    bool p = false;
    if (i < N) {
      int lab = instb[i];
      if (tmb[i] <= 0.5f) lab = 0;
      p = (lab == 0);
    }
    unsigned long long m = __ballot(p);
    if (lane == 0) s_wcnt[wave] = __popcll(m);
    __syncthreads();
    int pos = s_count;
    for (int w = 0; w < wave; ++w) pos += s_wcnt[w];
    if (p) {
      pos += __popcll(m & ((1ull << lane) - 1ull));
      if (pos < BG_SAMPLE) s_bgidx[pos] = i;
    }
    __syncthreads();
    if (t == 0) s_count += s_wcnt[0] + s_wcnt[1] + s_wcnt[2] + s_wcnt[3];
    __syncthreads();
  }
  if (s_count < BG_SAMPLE) {
    for (int base = 0; base < N; base += 256) {
      if (s_count >= BG_SAMPLE) break;
      int i = base + t;
      bool p = false;
      if (i < N) {
        int lab = instb[i];
        if (tmb[i] <= 0.5f) lab = 0;
        p = (lab != 0);
      }
      unsigned long long m = __ballot(p);
      if (lane == 0) s_wcnt[wave] = __popcll(m);
      __syncthreads();
      int pos = s_count;
      for (int w = 0; w < wave; ++w) pos += s_wcnt[w];
      if (p) {
        pos += __popcll(m & ((1ull << lane) - 1ull));
        if (pos < BG_SAMPLE) s_bgidx[pos] = i;
      }
      __syncthreads();
      if (t == 0) s_count += s_wcnt[0] + s_wcnt[1] + s_wcnt[2] + s_wcnt[3];
      __syncthreads();
    }
  }
  __syncthreads();

  __shared__ float ebg[BG_SAMPLE][4];
  const float* embb = emb + (size_t)b * 4 * N;
  for (int j = t; j < BG_SAMPLE; j += 256) {
    int i = s_bgidx[j];
    ebg[j][0] = embb[i];
    ebg[j][1] = embb[(size_t)N + i];
    ebg[j][2] = embb[(size_t)2 * N + i];
    ebg[j][3] = embb[(size_t)3 * N + i];
  }
  __shared__ float mean[KI][4];
  float* gmean = ws + (size_t)B * 224 + (size_t)b * 128;
  if (t < 128) (&mean[0][0])[t] = gmean[t];
  __syncthreads();

  const float coef = 1.0f - expf(-10.0f / 32.0f);
  float local = 0.f;
  for (int idx = t; idx < 31 * BG_SAMPLE; idx += 256) {
    int k = 1 + idx / BG_SAMPLE, j = idx % BG_SAMPLE;
    float d0 = ebg[j][0] - mean[k][0];
    float d1 = ebg[j][1] - mean[k][1];
    float d2 = ebg[j][2] - mean[k][2];
    float d3 = ebg[j][3] - mean[k][3];
    float dd = sqrtf(d0 * d0 + d1 * d1 + d2 * d2 + d3 * d3);
    float a = fmaxf(3.0f - coef * dd, 0.f);
    local += logf(a * a + 1.f);
  }
  float w = waveReduceSum(local);
  __shared__ float red[4];
  if (lane == 0) red[wave] = w;
  __syncthreads();
  if (t == 0) {
    float* gmisc = ws + (size_t)B * 224 + (size_t)B * 128 + (size_t)b * 4;
    gmisc[2] = (red[0] + red[1] + red[2] + red[3]) * (1.0f / BG_SAMPLE);
  }
}

__global__ __launch_bounds__(256)
void pass2_kernel(const float* __restrict__ emb, const int* __restrict__ inst,
                  const float* __restrict__ tmask, const float* __restrict__ maxd,
                  float* __restrict__ ws, int N, int B, int bpb)
{
  const int b = blockIdx.y;
  const int t = threadIdx.x;
  __shared__ float meanT[4][KI];
  __shared__ float scal[KI];
  __shared__ unsigned vacc[4][KI];   // pk (valsum, cnt) per wave copy
  float* gmean = ws + (size_t)B * 224 + (size_t)b * 128;
  if (t < 128) { int d = t & 3, k = t >> 2; meanT[d][k] = gmean[t]; }
  if (t < KI) scal[t] = expf(maxd[b * KI + t]);
  for (int i = t; i < 4 * KI; i += 256) (&vacc[0][0])[i] = 0u;
  __syncthreads();

  unsigned* va = vacc[t >> 6];
  const unsigned vbase = lds_off(va);
  const size_t off = (size_t)b * N;
  const int N4 = N >> 2;
  const int4*   L4 = (const int4*)(inst + off);
  const float4* T4 = (const float4*)(tmask + off);
  const float4* E0 = (const float4*)(emb + (size_t)b * 4 * N);
  const float4* E1 = E0 + N4;
  const float4* E2 = E1 + N4;
  const float4* E3 = E2 + N4;
  const int stride = bpb * 256;

  for (int v = blockIdx.x * 256 + t; v < N4; v += stride) {
    int4   L  = L4[v];
    float4 T  = T4[v];
    float4 e0 = E0[v], e1 = E1[v], e2 = E2[v], e3 = E3[v];
#define PX2(lj, tj, a0, a1, a2, a3)                                   \
    {                                                                 \
      unsigned lab = (unsigned)((tj > 0.5f) ? (lj) : 0) & 31u;        \
      float d0 = (a0) - meanT[0][lab];                                \
      float d1 = (a1) - meanT[1][lab];                                \
      float d2 = (a2) - meanT[2][lab];                                \
      float d3 = (a3) - meanT[3][lab];                                \
      float dd = sqrtf(d0 * d0 + d1 * d1 + d2 * d2 + d3 * d3);        \
      float aa = fmaxf(scal[lab] * dd - 0.5f, 0.f);                   \
      ds_pk_add(vbase + (lab << 2), pkrtz(__logf(aa * aa + 1.f), 1.0f)); \
    }
    PX2(L.x, T.x, e0.x, e1.x, e2.x, e3.x)
    PX2(L.y, T.y, e0.y, e1.y, e2.y, e3.y)
    PX2(L.z, T.z, e0.z, e1.z, e2.z, e3.z)
    PX2(L.w, T.w, e0.w, e1.w, e2.w, e3.w)
#undef PX2
  }
  if (blockIdx.x == 0) {
    const float* eb = emb + (size_t)b * 4 * N;
    for (int i = (N4 << 2) + t; i < N; i += 256) {
      unsigned lab = (unsigned)((tmask[off + i] > 0.5f) ? inst[off + i] : 0) & 31u;
      float d0 = eb[i]               - meanT[0][lab];
      float d1 = eb[(size_t)N + i]   - meanT[1][lab];
      float d2 = eb[(size_t)2*N + i] - meanT[2][lab];
      float d3 = eb[(size_t)3*N + i] - meanT[3][lab];
      float dd = sqrtf(d0 * d0 + d1 * d1 + d2 * d2 + d3 * d3);
      float aa = fmaxf(scal[lab] * dd - 0.5f, 0.f);
      ds_pk_add(vbase + (lab << 2), pkrtz(__logf(aa * aa + 1.f), 1.0f));
    }
  }
  __syncthreads();
  float* g = ws + (size_t)b * 224;
  for (int i = t; i < KI; i += 256) {
    unsigned u0 = vacc[0][i], u1 = vacc[1][i], u2 = vacc[2][i], u3 = vacc[3][i];
    float slo = cvt_lo(u0) + cvt_lo(u1) + cvt_lo(u2) + cvt_lo(u3);  // valsum
    float shi = cvt_hi(u0) + cvt_hi(u1) + cvt_hi(u2) + cvt_hi(u3);  // cnt
    if (slo != 0.f) atomicAdd(&g[192 + i], slo);
    if (shi != 0.f) atomicAdd(&g[i], shi);
  }
}

__global__ __launch_bounds__(64)
void final_kernel(const float* __restrict__ ws, float* __restrict__ out, int B)
{
  const int t = threadIdx.x;
  __shared__ float s[64];
  float tot = 0.f;
  if (t < B) {
    const float* gacc  = ws + (size_t)t * 224;
    const float* gmisc = ws + (size_t)B * 224 + (size_t)B * 128 + (size_t)t * 4;
    float lagg = 0.f;
    for (int k = 1; k < KI; ++k)
      lagg += gacc[192 + k] / fmaxf(gacc[k], 1.0f);
    lagg *= (1.0f / 31.0f);
    float ldis = (gmisc[0] + gmisc[2]) * (1.0f / 961.0f);  // (K-1)(K-2)+(K-1)
    tot = lagg + ldis + gmisc[1];
  }
  s[t] = tot;
  __syncthreads();
  if (t == 0) {
    float sum = 0.f;
    for (int b = 0; b < B; ++b) sum += s[b];
    out[0] = sum / (float)B;
  }
}

extern "C" void kernel_launch(void* const* d_in, const int* in_sizes, int n_in,
                              void* d_out, int out_size, void* d_ws, size_t ws_size,
                              hipStream_t stream)
{
  const float* emb   = (const float*)d_in[0];
  const int*   inst  = (const int*)d_in[1];
  const float* kern  = (const float*)d_in[2];
  const float* tmask = (const float*)d_in[3];
  const float* maxd  = (const float*)d_in[5];
  float* out = (float*)d_out;
  float* ws  = (float*)d_ws;

  const int B = in_sizes[5] / KI;          // 16
  const int N = in_sizes[1] / B;           // 409600
  const int bpb1 = 100;                    // pass1 blocks/batch (400 waves, 4 tiles each)
  const int bpb2 = 128;

  if (ws_size < (size_t)B * 356 * sizeof(float)) return;

  hipMemsetAsync(d_ws, 0, (size_t)B * 356 * sizeof(float), stream);
  pass1_kernel<<<dim3(bpb1, B), 256, 0, stream>>>(emb, inst, kern, tmask, ws, N, bpb1);
  stats_kernel<<<B, 256, 0, stream>>>(ws, B);
  bg_kernel<<<B, 256, 0, stream>>>(emb, inst, tmask, ws, N, B);
  pass2_kernel<<<dim3(bpb2, B), 256, 0, stream>>>(emb, inst, tmask, maxd, ws, N, B, bpb2);
  final_kernel<<<1, 64, 0, stream>>>(ws, out, B);
}

// Round 5
// 98.927 us; speedup vs baseline: 3.3808x; 1.2375x over previous
//
#include <hip/hip_runtime.h>

#define KI 32
#define BG_SAMPLE 100

// ws float layout (per batch b at b*224):
//   acc[224] = { cnt[32], cntk[32], sums d-major [4][32], valsum[32] }
// (mean region at B*224.. unused), misc[B][4] = {sum_pair,l_reg,sum_bg,pad}
// at B*224+B*128 + b*4. total B*356 floats.

typedef __attribute__((ext_vector_type(8))) _Float16 half8;
typedef __attribute__((ext_vector_type(4))) float f32x4;
typedef union { unsigned u[4]; half8 v; } hfrag;

static __device__ __forceinline__ unsigned pkrtz(float a, float b) {
  unsigned d;
  asm("v_cvt_pkrtz_f16_f32 %0, %1, %2" : "=v"(d) : "v"(a), "v"(b));
  return d;
}
static __device__ __forceinline__ unsigned ohpair16(int la, int lb_, int r) {
  return ((la == r) ? 0x3C00u : 0u) | ((lb_ == r) ? 0x3C000000u : 0u);
}
static __device__ __forceinline__ float waveReduceSum(float v) {
#pragma unroll
  for (int off = 32; off > 0; off >>= 1) v += __shfl_down(v, off, 64);
  return v;
}

// ---------------- pass1: streaming MFMA one-hot, reg-prefetch + f16 LDS ----
__global__ __launch_bounds__(256)
void pass1_kernel(const float* __restrict__ emb, const int* __restrict__ inst,
                  const float* __restrict__ kern, const float* __restrict__ tmask,
                  float* __restrict__ ws, int N, int bpb)
{
  const int b = blockIdx.y;
  const int t = threadIdx.x;
  const int lane = t & 63, w = t >> 6;
  const int c = lane & 15, g = lane >> 4;
  __shared__ int s_lab[4][256];
  __shared__ __align__(16) unsigned short s_embh[4][1024];  // 4 rows x 256 f16
  __shared__ float s_acc[160];                              // [label][5]
  for (int i = t; i < 160; i += 256) s_acc[i] = 0.f;
  __syncthreads();

  const size_t off = (size_t)b * N;
  const int*   instb = inst + off;
  const float* kernb = kern + off;
  const float* tmb   = tmask + off;
  const float* embb  = emb + (size_t)b * 4 * N;
  float* gout = ws + (size_t)b * 224;

  f32x4 acc0 = {0.f, 0.f, 0.f, 0.f};
  f32x4 acc1 = {0.f, 0.f, 0.f, 0.f};
  const int waves_total = bpb * 4;
  const int wave_id = blockIdx.x * 4 + w;
  const int tiles = N >> 8;

  int tile = wave_id;
  int4 L; float4 T, Kk, E0, E1, E2, E3;
  if (tile < tiles) {
    const int p0 = (tile << 8) + lane * 4;
    L  = *(const int4*)(instb + p0);
    T  = *(const float4*)(tmb + p0);
    Kk = *(const float4*)(kernb + p0);
    E0 = *(const float4*)(embb + p0);
    E1 = *(const float4*)(embb + (size_t)N + p0);
    E2 = *(const float4*)(embb + (size_t)2 * N + p0);
    E3 = *(const float4*)(embb + (size_t)3 * N + p0);
  }
  while (tile < tiles) {
    int4 lb;
    lb.x = (T.x > 0.5f && Kk.x > 0.5f) ? L.x : 0;
    lb.y = (T.y > 0.5f && Kk.y > 0.5f) ? L.y : 0;
    lb.z = (T.z > 0.5f && Kk.z > 0.5f) ? L.z : 0;
    lb.w = (T.w > 0.5f && Kk.w > 0.5f) ? L.w : 0;
    *(int4*)&s_lab[w][lane * 4] = lb;
    uint2 r;
    r.x = pkrtz(E0.x, E0.y); r.y = pkrtz(E0.z, E0.w);
    *(uint2*)&s_embh[w][lane * 4] = r;
    r.x = pkrtz(E1.x, E1.y); r.y = pkrtz(E1.z, E1.w);
    *(uint2*)&s_embh[w][256 + lane * 4] = r;
    r.x = pkrtz(E2.x, E2.y); r.y = pkrtz(E2.z, E2.w);
    *(uint2*)&s_embh[w][512 + lane * 4] = r;
    r.x = pkrtz(E3.x, E3.y); r.y = pkrtz(E3.z, E3.w);
    *(uint2*)&s_embh[w][768 + lane * 4] = r;

    const int next = tile + waves_total;
    if (next < tiles) {                      // prefetch next tile into regs
      const int p0 = (next << 8) + lane * 4;
      L  = *(const int4*)(instb + p0);
      T  = *(const float4*)(tmb + p0);
      Kk = *(const float4*)(kernb + p0);
      E0 = *(const float4*)(embb + p0);
      E1 = *(const float4*)(embb + (size_t)N + p0);
      E2 = *(const float4*)(embb + (size_t)2 * N + p0);
      E3 = *(const float4*)(embb + (size_t)3 * N + p0);
    }
#pragma unroll
    for (int j = 0; j < 8; ++j) {
      const int p8 = j * 32 + g * 8;
      const int4 l0 = *(const int4*)&s_lab[w][p8];
      const int4 l1 = *(const int4*)&s_lab[w][p8 + 4];
      hfrag fa0, fa1, fb;
      fa0.u[0] = ohpair16(l0.x, l0.y, c);
      fa0.u[1] = ohpair16(l0.z, l0.w, c);
      fa0.u[2] = ohpair16(l1.x, l1.y, c);
      fa0.u[3] = ohpair16(l1.z, l1.w, c);
      fa1.u[0] = ohpair16(l0.x, l0.y, c + 16);
      fa1.u[1] = ohpair16(l0.z, l0.w, c + 16);
      fa1.u[2] = ohpair16(l1.x, l1.y, c + 16);
      fa1.u[3] = ohpair16(l1.z, l1.w, c + 16);
      if (c < 4) {
        fb.v = *(const half8*)&s_embh[w][c * 256 + p8];
      } else if (c == 4) {
        fb.u[0] = fb.u[1] = fb.u[2] = fb.u[3] = 0x3C003C00u;  // col4 = 1.0
      } else {
        fb.u[0] = fb.u[1] = fb.u[2] = fb.u[3] = 0u;
      }
      acc0 = __builtin_amdgcn_mfma_f32_16x16x32_f16(fa0.v, fb.v, acc0, 0, 0, 0);
      acc1 = __builtin_amdgcn_mfma_f32_16x16x32_f16(fa1.v, fb.v, acc1, 0, 0, 0);
    }
    tile = next;
  }

  if (c < 5) {
#pragma unroll
    for (int jj = 0; jj < 4; ++jj) {
      const int row = g * 4 + jj;
      atomicAdd(&s_acc[row * 5 + c], acc0[jj]);
      atomicAdd(&s_acc[(16 + row) * 5 + c], acc1[jj]);
    }
  }
  if ((N & 255) != 0 && blockIdx.x == 0) {    // generic tail (unused at 640x640)
    for (int i = ((N >> 8) << 8) + t; i < N; i += 256) {
      int lab = (tmb[i] > 0.5f && kernb[i] > 0.5f) ? (instb[i] & 31) : 0;
      atomicAdd(&gout[32 + lab], 1.f);
      atomicAdd(&gout[64 + lab],  embb[i]);
      atomicAdd(&gout[96 + lab],  embb[(size_t)N + i]);
      atomicAdd(&gout[128 + lab], embb[(size_t)2 * N + i]);
      atomicAdd(&gout[160 + lab], embb[(size_t)3 * N + i]);
    }
  }
  __syncthreads();
  if (t < 160) {
    float v = s_acc[t];
    if (v != 0.f) {
      const int row = t / 5, cc = t % 5;
      if (cc < 4) atomicAdd(&gout[64 + cc * 32 + row], v);
      else        atomicAdd(&gout[32 + row], v);
    }
  }
}

// ---------------- pass2: streaming MFMA one-hot over (val, 1) ---------------
__global__ __launch_bounds__(256)
void pass2_kernel(const float* __restrict__ emb, const int* __restrict__ inst,
                  const float* __restrict__ tmask, const float* __restrict__ maxd,
                  float* __restrict__ ws, int N, int B, int bpb)
{
  const int b = blockIdx.y;
  const int t = threadIdx.x;
  const int lane = t & 63, w = t >> 6;
  const int c = lane & 15, g = lane >> 4;
  __shared__ int s_lab[4][256];
  __shared__ __align__(16) unsigned short s_val[4][256];
  __shared__ __align__(16) float4 s_meanv[KI];
  __shared__ float s_scal[KI];
  __shared__ float s_acc[64];   // [0..31] valsum, [32..63] cnt
  float* gacc = ws + (size_t)b * 224;
  if (t < KI) {
    float inv = (t == 0) ? 0.f : 1.0f / fmaxf(gacc[32 + t], 1.0f);
    float4 m;
    m.x = gacc[64 + t]  * inv;
    m.y = gacc[96 + t]  * inv;
    m.z = gacc[128 + t] * inv;
    m.w = gacc[160 + t] * inv;
    s_meanv[t] = m;
    s_scal[t] = expf(maxd[b * KI + t]);
  }
  for (int i = t; i < 64; i += 256) s_acc[i] = 0.f;
  __syncthreads();

  const size_t off = (size_t)b * N;
  const int*   instb = inst + off;
  const float* tmb   = tmask + off;
  const float* embb  = emb + (size_t)b * 4 * N;

  f32x4 acc0 = {0.f, 0.f, 0.f, 0.f};
  f32x4 acc1 = {0.f, 0.f, 0.f, 0.f};
  const int waves_total = bpb * 4;
  const int wave_id = blockIdx.x * 4 + w;
  const int tiles = N >> 8;

  int tile = wave_id;
  int4 L; float4 T, E0, E1, E2, E3;
  if (tile < tiles) {
    const int p0 = (tile << 8) + lane * 4;
    L  = *(const int4*)(instb + p0);
    T  = *(const float4*)(tmb + p0);
    E0 = *(const float4*)(embb + p0);
    E1 = *(const float4*)(embb + (size_t)N + p0);
    E2 = *(const float4*)(embb + (size_t)2 * N + p0);
    E3 = *(const float4*)(embb + (size_t)3 * N + p0);
  }
  while (tile < tiles) {
    int4 lb;
    lb.x = (T.x > 0.5f) ? (L.x & 31) : 0;
    lb.y = (T.y > 0.5f) ? (L.y & 31) : 0;
    lb.z = (T.z > 0.5f) ? (L.z & 31) : 0;
    lb.w = (T.w > 0.5f) ? (L.w & 31) : 0;
    *(int4*)&s_lab[w][lane * 4] = lb;
    float v0, v1, v2, v3;
#define VALC(res, li, a0, a1, a2, a3) {                                  \
      float4 mn = s_meanv[li];                                           \
      float sc = s_scal[li];                                             \
      float d0 = (a0) - mn.x, d1 = (a1) - mn.y;                          \
      float d2 = (a2) - mn.z, d3 = (a3) - mn.w;                          \
      float dd = sqrtf(d0 * d0 + d1 * d1 + d2 * d2 + d3 * d3);           \
      float aa = fmaxf(sc * dd - 0.5f, 0.f);                             \
      res = __logf(aa * aa + 1.f); }
    VALC(v0, lb.x, E0.x, E1.x, E2.x, E3.x)
    VALC(v1, lb.y, E0.y, E1.y, E2.y, E3.y)
    VALC(v2, lb.z, E0.z, E1.z, E2.z, E3.z)
    VALC(v3, lb.w, E0.w, E1.w, E2.w, E3.w)
#undef VALC
    uint2 vr;
    vr.x = pkrtz(v0, v1); vr.y = pkrtz(v2, v3);
    *(uint2*)&s_val[w][lane * 4] = vr;

    const int next = tile + waves_total;
    if (next < tiles) {
      const int p0 = (next << 8) + lane * 4;
      L  = *(const int4*)(instb + p0);
      T  = *(const float4*)(tmb + p0);
      E0 = *(const float4*)(embb + p0);
      E1 = *(const float4*)(embb + (size_t)N + p0);
      E2 = *(const float4*)(embb + (size_t)2 * N + p0);
      E3 = *(const float4*)(embb + (size_t)3 * N + p0);
    }
#pragma unroll
    for (int j = 0; j < 8; ++j) {
      const int p8 = j * 32 + g * 8;
      const int4 l0 = *(const int4*)&s_lab[w][p8];
      const int4 l1 = *(const int4*)&s_lab[w][p8 + 4];
      hfrag fa0, fa1, fb;
      fa0.u[0] = ohpair16(l0.x, l0.y, c);
      fa0.u[1] = ohpair16(l0.z, l0.w, c);
      fa0.u[2] = ohpair16(l1.x, l1.y, c);
      fa0.u[3] = ohpair16(l1.z, l1.w, c);
      fa1.u[0] = ohpair16(l0.x, l0.y, c + 16);
      fa1.u[1] = ohpair16(l0.z, l0.w, c + 16);
      fa1.u[2] = ohpair16(l1.x, l1.y, c + 16);
      fa1.u[3] = ohpair16(l1.z, l1.w, c + 16);
      if (c == 0) {
        fb.v = *(const half8*)&s_val[w][p8];
      } else if (c == 1) {
        fb.u[0] = fb.u[1] = fb.u[2] = fb.u[3] = 0x3C003C00u;  // col1 = 1.0
      } else {
        fb.u[0] = fb.u[1] = fb.u[2] = fb.u[3] = 0u;
      }
      acc0 = __builtin_amdgcn_mfma_f32_16x16x32_f16(fa0.v, fb.v, acc0, 0, 0, 0);
      acc1 = __builtin_amdgcn_mfma_f32_16x16x32_f16(fa1.v, fb.v, acc1, 0, 0, 0);
    }
    tile = next;
  }

  if (c < 2) {
#pragma unroll
    for (int jj = 0; jj < 4; ++jj) {
      const int row = g * 4 + jj;
      atomicAdd(&s_acc[c * 32 + row], acc0[jj]);
      atomicAdd(&s_acc[c * 32 + 16 + row], acc1[jj]);
    }
  }
  if ((N & 255) != 0 && blockIdx.x == 0) {    // generic tail (unused here)
    for (int i = ((N >> 8) << 8) + t; i < N; i += 256) {
      int lab = (tmb[i] > 0.5f) ? (instb[i] & 31) : 0;
      float4 mn = s_meanv[lab];
      float sc = s_scal[lab];
      float d0 = embb[i] - mn.x;
      float d1 = embb[(size_t)N + i] - mn.y;
      float d2 = embb[(size_t)2 * N + i] - mn.z;
      float d3 = embb[(size_t)3 * N + i] - mn.w;
      float dd = sqrtf(d0 * d0 + d1 * d1 + d2 * d2 + d3 * d3);
      float aa = fmaxf(sc * dd - 0.5f, 0.f);
      atomicAdd(&gacc[192 + lab], __logf(aa * aa + 1.f));
      atomicAdd(&gacc[lab], 1.f);
    }
  }
  __syncthreads();
  if (t < 64) {
    float v = s_acc[t];
    if (v != 0.f) {
      if (t < 32) atomicAdd(&gacc[192 + t], v);   // valsum
      else        atomicAdd(&gacc[t - 32], v);    // cnt
    }
  }
}

// ------------- bg_kernel: means + pairwise + l_reg + bg term ---------------
__global__ __launch_bounds__(256)
void bg_kernel(const float* __restrict__ emb, const int* __restrict__ inst,
               const float* __restrict__ tmask, float* __restrict__ ws, int N, int B)
{
  const int b = blockIdx.x;
  const int t = threadIdx.x;
  const int lane = t & 63, wave = t >> 6;
  float* gacc = ws + (size_t)b * 224;
  __shared__ float mean[KI][4];
  __shared__ int s_bgidx[BG_SAMPLE];
  __shared__ int s_count;
  __shared__ int s_wcnt[4];
  if (t == 0) s_count = 0;
  if (t < KI) {
    float inv = (t == 0) ? 0.f : 1.0f / fmaxf(gacc[32 + t], 1.0f);
    mean[t][0] = gacc[64 + t]  * inv;
    mean[t][1] = gacc[96 + t]  * inv;
    mean[t][2] = gacc[128 + t] * inv;
    mean[t][3] = gacc[160 + t] * inv;
  }
  __syncthreads();
  const int*   instb = inst + (size_t)b * N;
  const float* tmb   = tmask + (size_t)b * N;

  for (int base = 0; base < N; base += 256) {
    if (s_count >= BG_SAMPLE) break;
    int i = base + t;
    bool p = false;
    if (i < N) {
      int lab = instb[i];
      if (tmb[i] <= 0.5f) lab = 0;
      p = (lab == 0);
    }
    unsigned long long m = __ballot(p);
    if (lane == 0) s_wcnt[wave] = __popcll(m);
    __syncthreads();
    int pos = s_count;
    for (int ww = 0; ww < wave; ++ww) pos += s_wcnt[ww];
    if (p) {
      pos += __popcll(m & ((1ull << lane) - 1ull));
      if (pos < BG_SAMPLE) s_bgidx[pos] = i;
    }
    __syncthreads();
    if (t == 0) s_count += s_wcnt[0] + s_wcnt[1] + s_wcnt[2] + s_wcnt[3];
    __syncthreads();
  }
  if (s_count < BG_SAMPLE) {   // stable-argsort fallback: first non-bg indices
    for (int base = 0; base < N; base += 256) {
      if (s_count >= BG_SAMPLE) break;
      int i = base + t;
      bool p = false;
      if (i < N) {
        int lab = instb[i];
        if (tmb[i] <= 0.5f) lab = 0;
        p = (lab != 0);
      }
      unsigned long long m = __ballot(p);
      if (lane == 0) s_wcnt[wave] = __popcll(m);
      __syncthreads();
      int pos = s_count;
      for (int ww = 0; ww < wave; ++ww) pos += s_wcnt[ww];
      if (p) {
        pos += __popcll(m & ((1ull << lane) - 1ull));
        if (pos < BG_SAMPLE) s_bgidx[pos] = i;
      }
      __syncthreads();
      if (t == 0) s_count += s_wcnt[0] + s_wcnt[1] + s_wcnt[2] + s_wcnt[3];
      __syncthreads();
    }
  }
  __syncthreads();

  __shared__ float ebg[BG_SAMPLE][4];
  const float* embb = emb + (size_t)b * 4 * N;
  for (int j = t; j < BG_SAMPLE; j += 256) {
    int i = s_bgidx[j];
    ebg[j][0] = embb[i];
    ebg[j][1] = embb[(size_t)N + i];
    ebg[j][2] = embb[(size_t)2 * N + i];
    ebg[j][3] = embb[(size_t)3 * N + i];
  }
  __syncthreads();

  const float coef = 1.0f - expf(-10.0f / 32.0f);
  float lp = 0.f;
  for (int idx = t; idx < 31 * 31; idx += 256) {
    int i = 1 + idx / 31, j = 1 + idx % 31;
    if (i == j) continue;
    float d0 = mean[i][0] - mean[j][0];
    float d1 = mean[i][1] - mean[j][1];
    float d2 = mean[i][2] - mean[j][2];
    float d3 = mean[i][3] - mean[j][3];
    float pd = sqrtf(d0 * d0 + d1 * d1 + d2 * d2 + d3 * d3);
    float a = fmaxf(3.0f - coef * pd, 0.f);
    lp += logf(a * a + 1.f);
  }
  float lr = 0.f;
  for (int k = t; k < KI; k += 256) {
    float n = sqrtf(mean[k][0] * mean[k][0] + mean[k][1] * mean[k][1] +
                    mean[k][2] * mean[k][2] + mean[k][3] * mean[k][3]);
    lr += logf(n + 1.f);
  }
  float lbg = 0.f;
  for (int idx = t; idx < 31 * BG_SAMPLE; idx += 256) {
    int k = 1 + idx / BG_SAMPLE, j = idx % BG_SAMPLE;
    float d0 = ebg[j][0] - mean[k][0];
    float d1 = ebg[j][1] - mean[k][1];
    float d2 = ebg[j][2] - mean[k][2];
    float d3 = ebg[j][3] - mean[k][3];
    float dd = sqrtf(d0 * d0 + d1 * d1 + d2 * d2 + d3 * d3);
    float a = fmaxf(3.0f - coef * dd, 0.f);
    lbg += logf(a * a + 1.f);
  }
  float a0 = waveReduceSum(lp);
  float a1 = waveReduceSum(lr);
  float a2 = waveReduceSum(lbg);
  __shared__ float red[3][4];
  if (lane == 0) { red[0][wave] = a0; red[1][wave] = a1; red[2][wave] = a2; }
  __syncthreads();
  if (t == 0) {
    float* gmisc = ws + (size_t)B * 224 + (size_t)B * 128 + (size_t)b * 4;
    gmisc[0] = red[0][0] + red[0][1] + red[0][2] + red[0][3];
    gmisc[1] = (red[1][0] + red[1][1] + red[1][2] + red[1][3]) * (0.001f / 32.0f);
    gmisc[2] = (red[2][0] + red[2][1] + red[2][2] + red[2][3]) * (1.0f / BG_SAMPLE);
  }
}

__global__ __launch_bounds__(64)
void final_kernel(const float* __restrict__ ws, float* __restrict__ out, int B)
{
  const int t = threadIdx.x;
  __shared__ float s[64];
  float tot = 0.f;
  if (t < B) {
    const float* gacc  = ws + (size_t)t * 224;
    const float* gmisc = ws + (size_t)B * 224 + (size_t)B * 128 + (size_t)t * 4;
    float lagg = 0.f;
    for (int k = 1; k < KI; ++k)
      lagg += gacc[192 + k] / fmaxf(gacc[k], 1.0f);
    lagg *= (1.0f / 31.0f);
    float ldis = (gmisc[0] + gmisc[2]) * (1.0f / 961.0f);  // (K-1)(K-2)+(K-1)
    tot = lagg + ldis + gmisc[1];
  }
  s[t] = tot;
  __syncthreads();
  if (t == 0) {
    float sum = 0.f;
    for (int b = 0; b < B; ++b) sum += s[b];
    out[0] = sum / (float)B;
  }
}

extern "C" void kernel_launch(void* const* d_in, const int* in_sizes, int n_in,
                              void* d_out, int out_size, void* d_ws, size_t ws_size,
                              hipStream_t stream)
{
  const float* emb   = (const float*)d_in[0];
  const int*   inst  = (const int*)d_in[1];
  const float* kern  = (const float*)d_in[2];
  const float* tmask = (const float*)d_in[3];
  const float* maxd  = (const float*)d_in[5];
  float* out = (float*)d_out;
  float* ws  = (float*)d_ws;

  const int B = in_sizes[5] / KI;          // 16
  const int N = in_sizes[1] / B;           // 409600
  const int bpb = 100;                     // 400 waves/batch, 4 tiles each

  if (ws_size < (size_t)B * 356 * sizeof(float)) return;

  hipMemsetAsync(d_ws, 0, (size_t)B * 356 * sizeof(float), stream);
  pass1_kernel<<<dim3(bpb, B), 256, 0, stream>>>(emb, inst, kern, tmask, ws, N, bpb);
  pass2_kernel<<<dim3(bpb, B), 256, 0, stream>>>(emb, inst, tmask, maxd, ws, N, B, bpb);
  bg_kernel<<<B, 256, 0, stream>>>(emb, inst, tmask, ws, N, B);
  final_kernel<<<1, 64, 0, stream>>>(ws, out, B);
}